// Round 2
// baseline (148.720 us; speedup 1.0000x reference)
//
#include <hip/hip_runtime.h>
#include <math.h>

#define BB 2
#define NPTS 1024
#define KK 64
#define NSZ 32
#define CC 1331      // 11^3
#define FF 32
#define RAD2 1.0f

// ---------------- K1: feature MLPs + score + tgt (-2x,-2y,-2z,|t|^2) ----------------
__global__ __launch_bounds__(256)
void k_features(const float* __restrict__ src_pts, const float* __restrict__ tgt_pts,
                const float* __restrict__ W1, const float* __restrict__ b1,
                const float* __restrict__ W2, const float* __restrict__ b2,
                const float* __restrict__ Ww1, const float* __restrict__ bw1,
                const float* __restrict__ Ww2, const float* __restrict__ bw2,
                float* __restrict__ src_feat, float* __restrict__ tgt_feat,
                float* __restrict__ tgt_m2, float* __restrict__ score)
{
    int gid = blockIdx.x * blockDim.x + threadIdx.x;
    if (gid >= 2 * BB * NPTS) return;
    int isTgt = gid >= BB * NPTS;
    int pn = gid & (BB * NPTS - 1);
    int b = pn >> 10, n = pn & 1023;
    const float* pts = isTgt ? tgt_pts : src_pts;
    float p[6];
#pragma unroll
    for (int i = 0; i < 6; i++) p[i] = pts[(b * 6 + i) * NPTS + n];
    float h[FF];
#pragma unroll
    for (int j = 0; j < FF; j++) {
        float a = b1[j];
#pragma unroll
        for (int i = 0; i < 6; i++) a = fmaf(p[i], W1[i * FF + j], a);
        h[j] = fmaxf(a, 0.0f);
    }
    float ft[FF];
#pragma unroll
    for (int j = 0; j < FF; j++) {
        float a = b2[j];
#pragma unroll
        for (int i = 0; i < FF; i++) a = fmaf(h[i], W2[i * FF + j], a);
        ft[j] = fmaxf(a, 0.0f);
    }
    float* fo = isTgt ? tgt_feat : src_feat;
#pragma unroll
    for (int j = 0; j < FF; j++) fo[(b * NPTS + n) * FF + j] = ft[j];
    if (isTgt) {
        float x = p[0], y = p[1], z = p[2];
        float4 v;
        v.x = -2.0f * x; v.y = -2.0f * y; v.z = -2.0f * z;
        v.w = x * x + y * y + z * z;
        ((float4*)tgt_m2)[b * NPTS + n] = v;
    } else {
        float acc = bw2[0];
#pragma unroll
        for (int j = 0; j < 16; j++) {
            float a = bw1[j];
#pragma unroll
            for (int i = 0; i < FF; i++) a = fmaf(ft[i], Ww1[i * 16 + j], a);
            acc = fmaf(fmaxf(a, 0.0f), Ww2[j], acc);
        }
        score[b * NPTS + n] = acc;
    }
}

// ---------------- K2: top-K via bitonic sort (descending, ties -> lower idx) ----------------
__global__ __launch_bounds__(1024)
void k_topk(const float* __restrict__ score, const float* __restrict__ src_pts,
            const float* __restrict__ R,
            int* __restrict__ key_idx, float* __restrict__ kxyz,
            float* __restrict__ kxyz_t, float* __restrict__ out_kxyz)
{
    __shared__ float s[NPTS];
    __shared__ int id[NPTS];
    int b = blockIdx.x, t = threadIdx.x;
    s[t] = score[b * NPTS + t];
    id[t] = t;
    __syncthreads();
    for (int k = 2; k <= NPTS; k <<= 1) {
        for (int j = k >> 1; j > 0; j >>= 1) {
            int ixj = t ^ j;
            if (ixj > t) {
                float s1 = s[t], s2 = s[ixj];
                int i1 = id[t], i2 = id[ixj];
                bool after = (s1 < s2) || (s1 == s2 && i1 > i2);
                bool up = (t & k) == 0;
                if (up ? after : !after) {
                    s[t] = s2; s[ixj] = s1; id[t] = i2; id[ixj] = i1;
                }
            }
            __syncthreads();
        }
    }
    if (t < KK) {
        int kidx = id[t];
        key_idx[b * KK + t] = kidx;
        float x = src_pts[(b * 6 + 0) * NPTS + kidx];
        float y = src_pts[(b * 6 + 1) * NPTS + kidx];
        float z = src_pts[(b * 6 + 2) * NPTS + kidx];
        int o = (b * KK + t) * 3;
        kxyz[o] = x; kxyz[o + 1] = y; kxyz[o + 2] = z;
        out_kxyz[o] = x; out_kxyz[o + 1] = y; out_kxyz[o + 2] = z;
#pragma unroll
        for (int i = 0; i < 3; i++)
            kxyz_t[o + i] = R[i * 3 + 0] * x + R[i * 3 + 1] * y + R[i * 3 + 2] * z;
    }
}

// ---------------- K3: radius grouping + src dfe + maxpool ----------------
__global__ __launch_bounds__(64)
void k_group_emb(const float* __restrict__ kxyz, const int* __restrict__ key_idx,
                 const float* __restrict__ src_feat,
                 const float* __restrict__ Wd1, const float* __restrict__ bd1,
                 const float* __restrict__ Wd2, const float* __restrict__ bd2,
                 float* __restrict__ src_emb)
{
    int b = blockIdx.x / KK, kk = blockIdx.x % KK;
    int t = threadIdx.x;
    __shared__ float kx[KK][3];
    __shared__ float emb[NSZ][FF];
    kx[t][0] = kxyz[(b * KK + t) * 3 + 0];
    kx[t][1] = kxyz[(b * KK + t) * 3 + 1];
    kx[t][2] = kxyz[(b * KK + t) * 3 + 2];
    __syncthreads();
    float cx = kx[kk][0], cy = kx[kk][1], cz = kx[kk][2];
    float dx = kx[t][0] - cx, dy = kx[t][1] - cy, dz = kx[t][2] - cz;
    float sq = dx * dx + dy * dy + dz * dz;
    unsigned long long mask = __ballot(sq <= RAD2);
    if (t < NSZ) {
        int cnt = __popcll(mask);
        int want = (t < cnt) ? t : 0;
        unsigned long long mm = mask;
        for (int q = 0; q < want; q++) mm &= (mm - 1);
        int g = __ffsll(mm) - 1;
        float xr = kx[g][0] - cx, yr = kx[g][1] - cy, zr = kx[g][2] - cz;
        int orig = key_idx[b * KK + g];
        const float* fz = &src_feat[(b * NPTS + orig) * FF];
        float fr[FF];
#pragma unroll
        for (int i = 0; i < FF; i++) fr[i] = fz[i];
        float h[FF];
#pragma unroll
        for (int j = 0; j < FF; j++) {
            float a = bd1[j];
            a = fmaf(xr, Wd1[0 * FF + j], a);
            a = fmaf(yr, Wd1[1 * FF + j], a);
            a = fmaf(zr, Wd1[2 * FF + j], a);
#pragma unroll
            for (int i = 0; i < FF; i++) a = fmaf(fr[i], Wd1[(3 + i) * FF + j], a);
            h[j] = fmaxf(a, 0.0f);
        }
#pragma unroll
        for (int j = 0; j < FF; j++) {
            float a = bd2[j];
#pragma unroll
            for (int i = 0; i < FF; i++) a = fmaf(h[i], Wd2[i * FF + j], a);
            emb[t][j] = fmaxf(a, 0.0f);
        }
    }
    __syncthreads();
    if (t < FF) {
        float m = emb[0][t];
#pragma unroll
        for (int s2 = 1; s2 < NSZ; s2++) m = fmaxf(m, emb[s2][t]);
        src_emb[(b * KK + kk) * FF + t] = m;
    }
}

// ---------------- K4a: exact NN argmin, 128 cand x 4 n-chunks per block ----------------
// d' = |t|^2 - 2*cand.t  (cand-norm constant under argmin). Reads are wave-uniform
// -> scalar cache; no data staging, only a 4KB merge buffer -> 32 waves/CU.
__global__ __launch_bounds__(512)
void k_nn(const float* __restrict__ kxyz_t, const float* __restrict__ tgt_m2,
          int* __restrict__ nn_idx)
{
    const int NCH = 11;                  // ceil(1331/128)
    int bid = blockIdx.x;
    int cchunk = bid % NCH;
    int bk = bid / NCH;                  // 0..127
    int b = bk >> 6;
    int t = threadIdx.x;
    int cl = t & 127;
    int nch = t >> 7;                    // uniform within each wave
    int c = cchunk * 128 + cl;
    int cc = min(c, CC - 1);             // clamp: keeps control flow uniform
    int ix = cc / 121;
    int rem = cc - ix * 121;
    int iy = rem / 11;
    int iz = rem - iy * 11;
    float cx = kxyz_t[bk * 3 + 0] + (-2.0f + ix * 0.4f);
    float cy = kxyz_t[bk * 3 + 1] + (-2.0f + iy * 0.4f);
    float cz = kxyz_t[bk * 3 + 2] + (-2.0f + iz * 0.4f);
    const float4* pts = (const float4*)tgt_m2 + b * NPTS + (nch << 8);
    float best = 3.0e38f;
    int bn = 0;
#pragma unroll 8
    for (int i = 0; i < 256; i++) {
        float4 v = pts[i];               // wave-uniform address -> s_load
        float d = fmaf(cx, v.x, fmaf(cy, v.y, fmaf(cz, v.z, v.w)));
        if (d < best) { best = d; bn = i; }   // strict <: first-min
    }
    __shared__ float2 mb[512];
    mb[t] = make_float2(best, __int_as_float(bn + (nch << 8)));
    __syncthreads();
    if (t < 128 && c < CC) {
        float2 r = mb[t];
#pragma unroll
        for (int q = 1; q < 4; q++) {
            float2 o = mb[t + q * 128];
            if (o.x < r.x) r = o;        // tie -> lower chunk -> lower n: matches argmin
        }
        nn_idx[bk * CC + c] = __float_as_int(r.y);
    }
}

// ---------------- K4b: gather NN -> dfe MLP -> sim (weights via scalar loads) ----------------
__global__ __launch_bounds__(256)
void k_mlp(const float* __restrict__ kxyz_t, const float* __restrict__ tgt_m2,
           const float* __restrict__ tgt_feat, const float* __restrict__ src_emb,
           const int* __restrict__ nn_idx,
           const float* __restrict__ Wd1, const float* __restrict__ bd1,
           const float* __restrict__ Wd2, const float* __restrict__ bd2,
           float* __restrict__ sim)
{
    const int NCH = 6;                   // ceil(1331/256)
    int bid = blockIdx.x;
    int chunk = bid % NCH;
    int bk = bid / NCH;
    int b = bk >> 6;
    int t = threadIdx.x;
    int c = chunk * 256 + t;
    int cc = min(c, CC - 1);
    int ix = cc / 121;
    int rem = cc - ix * 121;
    int iy = rem / 11;
    int iz = rem - iy * 11;
    float cx = kxyz_t[bk * 3 + 0] + (-2.0f + ix * 0.4f);
    float cy = kxyz_t[bk * 3 + 1] + (-2.0f + iy * 0.4f);
    float cz = kxyz_t[bk * 3 + 2] + (-2.0f + iz * 0.4f);
    int bn = nn_idx[bk * CC + cc];
    float4 nv = ((const float4*)tgt_m2)[b * NPTS + bn];
    // nv = (-2x,-2y,-2z,.): x = -0.5*nv.x exactly; x0 = cx - x = fma(0.5, nv.x, cx)
    float x0 = fmaf(0.5f, nv.x, cx);
    float x1 = fmaf(0.5f, nv.y, cy);
    float x2 = fmaf(0.5f, nv.z, cz);
    const float4* fz = (const float4*)&tgt_feat[(b * NPTS + bn) * FF];
    float fr[FF];
#pragma unroll
    for (int i = 0; i < FF / 4; i++) {
        float4 v = fz[i];
        fr[i * 4 + 0] = v.x; fr[i * 4 + 1] = v.y; fr[i * 4 + 2] = v.z; fr[i * 4 + 3] = v.w;
    }
    float h[FF];
#pragma unroll
    for (int j = 0; j < FF; j++) {
        float a = bd1[j];                // uniform -> scalar load
        a = fmaf(x0, Wd1[0 * FF + j], a);
        a = fmaf(x1, Wd1[1 * FF + j], a);
        a = fmaf(x2, Wd1[2 * FF + j], a);
        h[j] = a;
    }
#pragma unroll
    for (int i = 0; i < FF; i++) {
        float fi = fr[i];
#pragma unroll
        for (int j = 0; j < FF; j++)
            h[j] = fmaf(fi, Wd1[(3 + i) * FF + j], h[j]);
    }
#pragma unroll
    for (int j = 0; j < FF; j++) h[j] = fmaxf(h[j], 0.0f);
    float sv = 0.0f;
#pragma unroll
    for (int j = 0; j < FF; j++) {
        float a = bd2[j];
#pragma unroll
        for (int i = 0; i < FF; i++) a = fmaf(h[i], Wd2[i * FF + j], a);
        sv = fmaf(fmaxf(a, 0.0f), src_emb[bk * FF + j], sv);
    }
    if (c < CC) sim[bk * CC + c] = sv;
}

// ---------------- K5: softmax over candidates + weighted sum ----------------
__global__ __launch_bounds__(256)
void k_softmax(const float* __restrict__ sim, const float* __restrict__ kxyz_t,
               float* __restrict__ out_vcp)
{
    int bk = blockIdx.x;
    int t = threadIdx.x;
    __shared__ float red[256];
    __shared__ float4 red4[256];
    float kx = kxyz_t[bk * 3 + 0], ky = kxyz_t[bk * 3 + 1], kz = kxyz_t[bk * 3 + 2];
    float lm = -3.0e38f;
    for (int c = t; c < CC; c += 256) lm = fmaxf(lm, sim[bk * CC + c]);
    red[t] = lm;
    __syncthreads();
    for (int s2 = 128; s2 > 0; s2 >>= 1) {
        if (t < s2) red[t] = fmaxf(red[t], red[t + s2]);
        __syncthreads();
    }
    float m = red[0];
    float se = 0.f, sx = 0.f, sy = 0.f, sz = 0.f;
    for (int c = t; c < CC; c += 256) {
        float e = expf(sim[bk * CC + c] - m);
        int ix = c / 121, rem = c - ix * 121, iy = rem / 11, iz = rem - iy * 11;
        float cxx = kx + (-2.0f + ix * 0.4f);
        float cyy = ky + (-2.0f + iy * 0.4f);
        float czz = kz + (-2.0f + iz * 0.4f);
        se += e;
        sx = fmaf(e, cxx, sx);
        sy = fmaf(e, cyy, sy);
        sz = fmaf(e, czz, sz);
    }
    red4[t] = make_float4(se, sx, sy, sz);
    __syncthreads();
    for (int s2 = 128; s2 > 0; s2 >>= 1) {
        if (t < s2) {
            float4 a = red4[t], bq = red4[t + s2];
            red4[t] = make_float4(a.x + bq.x, a.y + bq.y, a.z + bq.z, a.w + bq.w);
        }
        __syncthreads();
    }
    if (t == 0) {
        float4 r = red4[0];
        out_vcp[bk * 3 + 0] = r.y / r.x;
        out_vcp[bk * 3 + 1] = r.z / r.x;
        out_vcp[bk * 3 + 2] = r.w / r.x;
    }
}

extern "C" void kernel_launch(void* const* d_in, const int* in_sizes, int n_in,
                              void* d_out, int out_size, void* d_ws, size_t ws_size,
                              hipStream_t stream)
{
    (void)in_sizes; (void)n_in; (void)out_size; (void)ws_size;
    const float* src_pts = (const float*)d_in[0];
    const float* tgt_pts = (const float*)d_in[1];
    const float* R_init  = (const float*)d_in[2];
    const float* W1  = (const float*)d_in[4];
    const float* b1  = (const float*)d_in[5];
    const float* W2  = (const float*)d_in[6];
    const float* b2  = (const float*)d_in[7];
    const float* Ww1 = (const float*)d_in[8];
    const float* bw1 = (const float*)d_in[9];
    const float* Ww2 = (const float*)d_in[10];
    const float* bw2 = (const float*)d_in[11];
    const float* Wd1 = (const float*)d_in[12];
    const float* bd1 = (const float*)d_in[13];
    const float* Wd2 = (const float*)d_in[14];
    const float* bd2 = (const float*)d_in[15];

    float* ws = (float*)d_ws;
    float* src_feat = ws;                              // B*N*F   = 65536
    float* tgt_feat = src_feat + BB * NPTS * FF;       // 65536
    float* tgt_m2   = tgt_feat + BB * NPTS * FF;       // B*N*4   = 8192
    float* score    = tgt_m2 + BB * NPTS * 4;          // 2048
    int*   key_idx  = (int*)(score + BB * NPTS);       // 128
    float* kxyz     = (float*)(key_idx + BB * KK);     // 384
    float* kxyz_t   = kxyz + BB * KK * 3;              // 384
    float* src_emb  = kxyz_t + BB * KK * 3;            // 4096
    float* sim      = src_emb + BB * KK * FF;          // B*K*C = 170368
    int*   nn_idx   = (int*)(sim + BB * KK * CC);      // B*K*C = 170368

    float* out_kxyz = (float*)d_out;
    float* out_vcp  = out_kxyz + BB * KK * 3;

    k_features<<<(2 * BB * NPTS + 255) / 256, 256, 0, stream>>>(
        src_pts, tgt_pts, W1, b1, W2, b2, Ww1, bw1, Ww2, bw2,
        src_feat, tgt_feat, tgt_m2, score);
    k_topk<<<BB, 1024, 0, stream>>>(score, src_pts, R_init,
                                    key_idx, kxyz, kxyz_t, out_kxyz);
    k_group_emb<<<BB * KK, 64, 0, stream>>>(kxyz, key_idx, src_feat,
                                            Wd1, bd1, Wd2, bd2, src_emb);
    k_nn<<<BB * KK * 11, 512, 0, stream>>>(kxyz_t, tgt_m2, nn_idx);
    k_mlp<<<BB * KK * 6, 256, 0, stream>>>(kxyz_t, tgt_m2, tgt_feat, src_emb,
                                           nn_idx, Wd1, bd1, Wd2, bd2, sim);
    k_softmax<<<BB * KK, 256, 0, stream>>>(sim, kxyz_t, out_vcp);
}

// Round 3
// 84.240 us; speedup vs baseline: 1.7654x; 1.7654x over previous
//
#include <hip/hip_runtime.h>
#include <math.h>

#define BB 2
#define NPTS 1024
#define KK 64
#define NSZ 32
#define CC 1331      // 11^3
#define FF 32
#define RAD2 1.0f

// ---------------- K1: feature MLPs + score + tgt (-2x,-2y,-2z,|t|^2) ----------------
__global__ __launch_bounds__(64)
void k_features(const float* __restrict__ src_pts, const float* __restrict__ tgt_pts,
                const float* __restrict__ W1, const float* __restrict__ b1,
                const float* __restrict__ W2, const float* __restrict__ b2,
                const float* __restrict__ Ww1, const float* __restrict__ bw1,
                const float* __restrict__ Ww2, const float* __restrict__ bw2,
                float* __restrict__ src_feat, float* __restrict__ tgt_feat,
                float* __restrict__ tgt_m2, float* __restrict__ score)
{
    int gid = blockIdx.x * blockDim.x + threadIdx.x;   // 0..4095
    int isTgt = gid >= BB * NPTS;
    int pn = gid & (BB * NPTS - 1);
    int b = pn >> 10, n = pn & 1023;
    const float* pts = isTgt ? tgt_pts : src_pts;
    float p[6];
#pragma unroll
    for (int i = 0; i < 6; i++) p[i] = pts[(b * 6 + i) * NPTS + n];
    float h[FF];
#pragma unroll
    for (int j = 0; j < FF; j++) {
        float a = b1[j];
#pragma unroll
        for (int i = 0; i < 6; i++) a = fmaf(p[i], W1[i * FF + j], a);
        h[j] = fmaxf(a, 0.0f);
    }
    float ft[FF];
#pragma unroll
    for (int j = 0; j < FF; j++) {
        float a = b2[j];
#pragma unroll
        for (int i = 0; i < FF; i++) a = fmaf(h[i], W2[i * FF + j], a);
        ft[j] = fmaxf(a, 0.0f);
    }
    float* fo = isTgt ? tgt_feat : src_feat;
#pragma unroll
    for (int j = 0; j < FF; j++) fo[(b * NPTS + n) * FF + j] = ft[j];
    if (isTgt) {
        float x = p[0], y = p[1], z = p[2];
        float4 v;
        v.x = -2.0f * x; v.y = -2.0f * y; v.z = -2.0f * z;
        v.w = x * x + y * y + z * z;
        ((float4*)tgt_m2)[b * NPTS + n] = v;
    } else {
        float acc = bw2[0];
#pragma unroll
        for (int j = 0; j < 16; j++) {
            float a = bw1[j];
#pragma unroll
            for (int i = 0; i < FF; i++) a = fmaf(ft[i], Ww1[i * 16 + j], a);
            acc = fmaf(fmaxf(a, 0.0f), Ww2[j], acc);
        }
        score[b * NPTS + n] = acc;
    }
}

// ---------------- K2: top-K bitonic; j<64 steps via shfl (no barrier) ----------------
__global__ __launch_bounds__(1024)
void k_topk(const float* __restrict__ score, const float* __restrict__ src_pts,
            const float* __restrict__ R,
            int* __restrict__ key_idx, float* __restrict__ kxyz,
            float* __restrict__ kxyz_t, float* __restrict__ out_kxyz)
{
    __shared__ float ss[NPTS];
    __shared__ int   si[NPTS];
    int b = blockIdx.x, t = threadIdx.x;
    float s = score[b * NPTS + t];
    int   id = t;
    for (int k = 2; k <= NPTS; k <<= 1) {
        for (int j = k >> 1; j > 0; j >>= 1) {
            float s2; int i2;
            if (j >= 64) {
                ss[t] = s; si[t] = id;
                __syncthreads();
                s2 = ss[t ^ j]; i2 = si[t ^ j];
                __syncthreads();
            } else {
                s2 = __shfl_xor(s, j, 64);
                i2 = __shfl_xor(id, j, 64);
            }
            // mAO: mine sorts after other in (desc score, asc idx) order
            bool mAO = (s < s2) || (s == s2 && id > i2);
            bool takeOther = ((mAO == ((t & j) == 0)) == ((t & k) == 0));
            if (takeOther) { s = s2; id = i2; }
        }
    }
    if (t < KK) {
        key_idx[b * KK + t] = id;
        float x = src_pts[(b * 6 + 0) * NPTS + id];
        float y = src_pts[(b * 6 + 1) * NPTS + id];
        float z = src_pts[(b * 6 + 2) * NPTS + id];
        int o = (b * KK + t) * 3;
        kxyz[o] = x; kxyz[o + 1] = y; kxyz[o + 2] = z;
        out_kxyz[o] = x; out_kxyz[o + 1] = y; out_kxyz[o + 2] = z;
#pragma unroll
        for (int i = 0; i < 3; i++)
            kxyz_t[o + i] = R[i * 3 + 0] * x + R[i * 3 + 1] * y + R[i * 3 + 2] * z;
    }
}

// ---------------- K3: radius grouping + src dfe + maxpool ----------------
__global__ __launch_bounds__(64)
void k_group_emb(const float* __restrict__ kxyz, const int* __restrict__ key_idx,
                 const float* __restrict__ src_feat,
                 const float* __restrict__ Wd1, const float* __restrict__ bd1,
                 const float* __restrict__ Wd2, const float* __restrict__ bd2,
                 float* __restrict__ src_emb)
{
    int b = blockIdx.x / KK, kk = blockIdx.x % KK;
    int t = threadIdx.x;
    __shared__ float kx[KK][3];
    __shared__ float emb[NSZ][FF];
    kx[t][0] = kxyz[(b * KK + t) * 3 + 0];
    kx[t][1] = kxyz[(b * KK + t) * 3 + 1];
    kx[t][2] = kxyz[(b * KK + t) * 3 + 2];
    __syncthreads();
    float cx = kx[kk][0], cy = kx[kk][1], cz = kx[kk][2];
    float dx = kx[t][0] - cx, dy = kx[t][1] - cy, dz = kx[t][2] - cz;
    float sq = dx * dx + dy * dy + dz * dz;
    unsigned long long mask = __ballot(sq <= RAD2);
    if (t < NSZ) {
        int cnt = __popcll(mask);
        int want = (t < cnt) ? t : 0;
        unsigned long long mm = mask;
        for (int q = 0; q < want; q++) mm &= (mm - 1);
        int g = __ffsll(mm) - 1;
        float xr = kx[g][0] - cx, yr = kx[g][1] - cy, zr = kx[g][2] - cz;
        int orig = key_idx[b * KK + g];
        const float* fz = &src_feat[(b * NPTS + orig) * FF];
        float fr[FF];
#pragma unroll
        for (int i = 0; i < FF; i++) fr[i] = fz[i];
        float h[FF];
#pragma unroll
        for (int j = 0; j < FF; j++) {
            float a = bd1[j];
            a = fmaf(xr, Wd1[0 * FF + j], a);
            a = fmaf(yr, Wd1[1 * FF + j], a);
            a = fmaf(zr, Wd1[2 * FF + j], a);
#pragma unroll
            for (int i = 0; i < FF; i++) a = fmaf(fr[i], Wd1[(3 + i) * FF + j], a);
            h[j] = fmaxf(a, 0.0f);
        }
#pragma unroll
        for (int j = 0; j < FF; j++) {
            float a = bd2[j];
#pragma unroll
            for (int i = 0; i < FF; i++) a = fmaf(h[i], Wd2[i * FF + j], a);
            emb[t][j] = fmaxf(a, 0.0f);
        }
    }
    __syncthreads();
    if (t < FF) {
        float m = emb[0][t];
#pragma unroll
        for (int s2 = 1; s2 < NSZ; s2++) m = fmaxf(m, emb[s2][t]);
        src_emb[(b * KK + kk) * FF + t] = m;
    }
}

// ---------------- K4: fused NN argmin (4 cands/thread, LDS broadcast) + dfe + sim ----
// Block: 256 threads = 4 ngroups x 64 lanes. Covers 256 candidates, full N=1024.
// ngroup g scans points [g*256,(g+1)*256); 4-way merge in LDS; then MLP on all lanes.
__global__ __launch_bounds__(256)
void k_nn_mlp(const float* __restrict__ kxyz_t, const float* __restrict__ tgt_m2,
              const float* __restrict__ tgt_feat, const float* __restrict__ src_emb,
              const float* __restrict__ Wd1, const float* __restrict__ bd1,
              const float* __restrict__ Wd2, const float* __restrict__ bd2,
              float* __restrict__ sim)
{
    const int CHUNKS = 6;                 // ceil(1331/256)
    int bid = blockIdx.x;
    int chunk = bid % CHUNKS;
    int bk = bid / CHUNKS;                // 0..127
    int b = bk >> 6;
    int t = threadIdx.x;
    int lane = t & 63;
    int ng = t >> 6;                      // 0..3, wave-uniform
    __shared__ float4 P[NPTS];            // 16 KB
    __shared__ float2 mb[4][256];         // 8 KB
    const float4* gp = (const float4*)tgt_m2 + (b << 10);
    for (int i = t; i < NPTS; i += 256) P[i] = gp[i];
    float kx = kxyz_t[bk * 3 + 0], ky = kxyz_t[bk * 3 + 1], kz = kxyz_t[bk * 3 + 2];
    float cxq[4], cyq[4], czq[4], best[4];
    int bn[4];
#pragma unroll
    for (int q = 0; q < 4; q++) {
        int c = chunk * 256 + q * 64 + lane;
        int cc = min(c, CC - 1);
        int ixv = cc / 121, rem = cc - ixv * 121, iyv = rem / 11, izv = rem - iyv * 11;
        cxq[q] = kx + (-2.0f + ixv * 0.4f);
        cyq[q] = ky + (-2.0f + iyv * 0.4f);
        czq[q] = kz + (-2.0f + izv * 0.4f);
        best[q] = 3.0e38f; bn[q] = 0;
    }
    __syncthreads();
    const int base = ng << 8;
#pragma unroll 4
    for (int i = 0; i < 256; i++) {
        float4 v = P[base + i];           // wave-uniform addr -> LDS broadcast
#pragma unroll
        for (int q = 0; q < 4; q++) {
            float d = fmaf(cxq[q], v.x, fmaf(cyq[q], v.y, fmaf(czq[q], v.z, v.w)));
            bool lt = d < best[q];        // strict <: first-min within chunk
            best[q] = lt ? d : best[q];
            bn[q] = lt ? (base + i) : bn[q];
        }
    }
#pragma unroll
    for (int q = 0; q < 4; q++)
        mb[ng][q * 64 + lane] = make_float2(best[q], __int_as_float(bn[q]));
    __syncthreads();
    // merge: thread t owns candidate c = chunk*256 + t; ascending g, strict <
    float2 r = mb[0][t];
#pragma unroll
    for (int g = 1; g < 4; g++) {
        float2 o = mb[g][t];
        if (o.x < r.x) r = o;             // ties -> lower chunk -> lower n
    }
    int nb = __float_as_int(r.y);
    int c = chunk * 256 + t;
    int cc = min(c, CC - 1);
    int ixv = cc / 121, rem = cc - ixv * 121, iyv = rem / 11, izv = rem - iyv * 11;
    float cx = kx + (-2.0f + ixv * 0.4f);
    float cy = ky + (-2.0f + iyv * 0.4f);
    float cz = kz + (-2.0f + izv * 0.4f);
    float4 nv = P[nb];
    // nv = (-2x,-2y,-2z,|t|^2): cand - x == fmaf(0.5, nv.x, cx) exactly
    float x0 = fmaf(0.5f, nv.x, cx);
    float x1 = fmaf(0.5f, nv.y, cy);
    float x2 = fmaf(0.5f, nv.z, cz);
    const float4* fz = (const float4*)&tgt_feat[((b << 10) + nb) * FF];
    float fr[FF];
#pragma unroll
    for (int i = 0; i < FF / 4; i++) {
        float4 v = fz[i];
        fr[i * 4 + 0] = v.x; fr[i * 4 + 1] = v.y; fr[i * 4 + 2] = v.z; fr[i * 4 + 3] = v.w;
    }
    float h[FF];
#pragma unroll
    for (int j = 0; j < FF; j++) {
        float a = bd1[j];                 // uniform -> scalar load
        a = fmaf(x0, Wd1[0 * FF + j], a);
        a = fmaf(x1, Wd1[1 * FF + j], a);
        a = fmaf(x2, Wd1[2 * FF + j], a);
        h[j] = a;
    }
#pragma unroll
    for (int i = 0; i < FF; i++) {
        float fi = fr[i];
#pragma unroll
        for (int j = 0; j < FF; j++)
            h[j] = fmaf(fi, Wd1[(3 + i) * FF + j], h[j]);
    }
#pragma unroll
    for (int j = 0; j < FF; j++) h[j] = fmaxf(h[j], 0.0f);
    float sv = 0.0f;
#pragma unroll
    for (int j = 0; j < FF; j++) {
        float a = bd2[j];
#pragma unroll
        for (int i = 0; i < FF; i++) a = fmaf(h[i], Wd2[i * FF + j], a);
        sv = fmaf(fmaxf(a, 0.0f), src_emb[bk * FF + j], sv);
    }
    if (c < CC) sim[bk * CC + c] = sv;
}

// ---------------- K5: softmax over candidates + weighted sum ----------------
__global__ __launch_bounds__(256)
void k_softmax(const float* __restrict__ sim, const float* __restrict__ kxyz_t,
               float* __restrict__ out_vcp)
{
    int bk = blockIdx.x;
    int t = threadIdx.x;
    __shared__ float red[256];
    __shared__ float4 red4[256];
    float kx = kxyz_t[bk * 3 + 0], ky = kxyz_t[bk * 3 + 1], kz = kxyz_t[bk * 3 + 2];
    float lm = -3.0e38f;
    for (int c = t; c < CC; c += 256) lm = fmaxf(lm, sim[bk * CC + c]);
    red[t] = lm;
    __syncthreads();
    for (int s2 = 128; s2 > 0; s2 >>= 1) {
        if (t < s2) red[t] = fmaxf(red[t], red[t + s2]);
        __syncthreads();
    }
    float m = red[0];
    float se = 0.f, sx = 0.f, sy = 0.f, sz = 0.f;
    for (int c = t; c < CC; c += 256) {
        float e = expf(sim[bk * CC + c] - m);
        int ix = c / 121, rem = c - ix * 121, iy = rem / 11, iz = rem - iy * 11;
        float cxx = kx + (-2.0f + ix * 0.4f);
        float cyy = ky + (-2.0f + iy * 0.4f);
        float czz = kz + (-2.0f + iz * 0.4f);
        se += e;
        sx = fmaf(e, cxx, sx);
        sy = fmaf(e, cyy, sy);
        sz = fmaf(e, czz, sz);
    }
    red4[t] = make_float4(se, sx, sy, sz);
    __syncthreads();
    for (int s2 = 128; s2 > 0; s2 >>= 1) {
        if (t < s2) {
            float4 a = red4[t], bq = red4[t + s2];
            red4[t] = make_float4(a.x + bq.x, a.y + bq.y, a.z + bq.z, a.w + bq.w);
        }
        __syncthreads();
    }
    if (t == 0) {
        float4 r = red4[0];
        out_vcp[bk * 3 + 0] = r.y / r.x;
        out_vcp[bk * 3 + 1] = r.z / r.x;
        out_vcp[bk * 3 + 2] = r.w / r.x;
    }
}

extern "C" void kernel_launch(void* const* d_in, const int* in_sizes, int n_in,
                              void* d_out, int out_size, void* d_ws, size_t ws_size,
                              hipStream_t stream)
{
    (void)in_sizes; (void)n_in; (void)out_size; (void)ws_size;
    const float* src_pts = (const float*)d_in[0];
    const float* tgt_pts = (const float*)d_in[1];
    const float* R_init  = (const float*)d_in[2];
    const float* W1  = (const float*)d_in[4];
    const float* b1  = (const float*)d_in[5];
    const float* W2  = (const float*)d_in[6];
    const float* b2  = (const float*)d_in[7];
    const float* Ww1 = (const float*)d_in[8];
    const float* bw1 = (const float*)d_in[9];
    const float* Ww2 = (const float*)d_in[10];
    const float* bw2 = (const float*)d_in[11];
    const float* Wd1 = (const float*)d_in[12];
    const float* bd1 = (const float*)d_in[13];
    const float* Wd2 = (const float*)d_in[14];
    const float* bd2 = (const float*)d_in[15];

    float* ws = (float*)d_ws;
    float* src_feat = ws;                              // B*N*F   = 65536
    float* tgt_feat = src_feat + BB * NPTS * FF;       // 65536
    float* tgt_m2   = tgt_feat + BB * NPTS * FF;       // B*N*4   = 8192
    float* score    = tgt_m2 + BB * NPTS * 4;          // 2048
    int*   key_idx  = (int*)(score + BB * NPTS);       // 128
    float* kxyz     = (float*)(key_idx + BB * KK);     // 384
    float* kxyz_t   = kxyz + BB * KK * 3;              // 384
    float* src_emb  = kxyz_t + BB * KK * 3;            // 4096
    float* sim      = src_emb + BB * KK * FF;          // B*K*C = 170368

    float* out_kxyz = (float*)d_out;
    float* out_vcp  = out_kxyz + BB * KK * 3;

    k_features<<<64, 64, 0, stream>>>(
        src_pts, tgt_pts, W1, b1, W2, b2, Ww1, bw1, Ww2, bw2,
        src_feat, tgt_feat, tgt_m2, score);
    k_topk<<<BB, 1024, 0, stream>>>(score, src_pts, R_init,
                                    key_idx, kxyz, kxyz_t, out_kxyz);
    k_group_emb<<<BB * KK, 64, 0, stream>>>(kxyz, key_idx, src_feat,
                                            Wd1, bd1, Wd2, bd2, src_emb);
    k_nn_mlp<<<BB * KK * 6, 256, 0, stream>>>(kxyz_t, tgt_m2, tgt_feat, src_emb,
                                              Wd1, bd1, Wd2, bd2, sim);
    k_softmax<<<BB * KK, 256, 0, stream>>>(sim, kxyz_t, out_vcp);
}

// Round 4
// 83.297 us; speedup vs baseline: 1.7854x; 1.0113x over previous
//
#include <hip/hip_runtime.h>
#include <math.h>

#define BB 2
#define NPTS 1024
#define KK 64
#define NSZ 32
#define CC 1331      // 11^3
#define FF 32
#define RAD2 1.0f

// ---------------- K1: feature MLPs + score + tgt (-2x,-2y,-2z,|t|^2) ----------------
__global__ __launch_bounds__(64)
void k_features(const float* __restrict__ src_pts, const float* __restrict__ tgt_pts,
                const float* __restrict__ W1, const float* __restrict__ b1,
                const float* __restrict__ W2, const float* __restrict__ b2,
                const float* __restrict__ Ww1, const float* __restrict__ bw1,
                const float* __restrict__ Ww2, const float* __restrict__ bw2,
                float* __restrict__ src_feat, float* __restrict__ tgt_feat,
                float* __restrict__ tgt_m2, float* __restrict__ score)
{
    int gid = blockIdx.x * blockDim.x + threadIdx.x;   // 0..4095
    int isTgt = gid >= BB * NPTS;
    int pn = gid & (BB * NPTS - 1);
    int b = pn >> 10, n = pn & 1023;
    const float* pts = isTgt ? tgt_pts : src_pts;
    float p[6];
#pragma unroll
    for (int i = 0; i < 6; i++) p[i] = pts[(b * 6 + i) * NPTS + n];
    float h[FF];
#pragma unroll
    for (int j = 0; j < FF; j++) {
        float a = b1[j];
#pragma unroll
        for (int i = 0; i < 6; i++) a = fmaf(p[i], W1[i * FF + j], a);
        h[j] = fmaxf(a, 0.0f);
    }
    float ft[FF];
#pragma unroll
    for (int j = 0; j < FF; j++) {
        float a = b2[j];
#pragma unroll
        for (int i = 0; i < FF; i++) a = fmaf(h[i], W2[i * FF + j], a);
        ft[j] = fmaxf(a, 0.0f);
    }
    float* fo = isTgt ? tgt_feat : src_feat;
#pragma unroll
    for (int j = 0; j < FF; j++) fo[(b * NPTS + n) * FF + j] = ft[j];
    if (isTgt) {
        float x = p[0], y = p[1], z = p[2];
        float4 v;
        v.x = -2.0f * x; v.y = -2.0f * y; v.z = -2.0f * z;
        v.w = x * x + y * y + z * z;
        ((float4*)tgt_m2)[b * NPTS + n] = v;
    } else {
        float acc = bw2[0];
#pragma unroll
        for (int j = 0; j < 16; j++) {
            float a = bw1[j];
#pragma unroll
            for (int i = 0; i < FF; i++) a = fmaf(ft[i], Ww1[i * 16 + j], a);
            acc = fmaf(fmaxf(a, 0.0f), Ww2[j], acc);
        }
        score[b * NPTS + n] = acc;
    }
}

// ---------------- K2: top-K bitonic; j<64 steps via shfl (no barrier) ----------------
__global__ __launch_bounds__(1024)
void k_topk(const float* __restrict__ score, const float* __restrict__ src_pts,
            const float* __restrict__ R,
            int* __restrict__ key_idx, float* __restrict__ kxyz,
            float* __restrict__ kxyz_t, float* __restrict__ out_kxyz)
{
    __shared__ float ss[NPTS];
    __shared__ int   si[NPTS];
    int b = blockIdx.x, t = threadIdx.x;
    float s = score[b * NPTS + t];
    int   id = t;
    for (int k = 2; k <= NPTS; k <<= 1) {
        for (int j = k >> 1; j > 0; j >>= 1) {
            float s2; int i2;
            if (j >= 64) {
                ss[t] = s; si[t] = id;
                __syncthreads();
                s2 = ss[t ^ j]; i2 = si[t ^ j];
                __syncthreads();
            } else {
                s2 = __shfl_xor(s, j, 64);
                i2 = __shfl_xor(id, j, 64);
            }
            bool mAO = (s < s2) || (s == s2 && id > i2);
            bool takeOther = ((mAO == ((t & j) == 0)) == ((t & k) == 0));
            if (takeOther) { s = s2; id = i2; }
        }
    }
    if (t < KK) {
        key_idx[b * KK + t] = id;
        float x = src_pts[(b * 6 + 0) * NPTS + id];
        float y = src_pts[(b * 6 + 1) * NPTS + id];
        float z = src_pts[(b * 6 + 2) * NPTS + id];
        int o = (b * KK + t) * 3;
        kxyz[o] = x; kxyz[o + 1] = y; kxyz[o + 2] = z;
        out_kxyz[o] = x; out_kxyz[o + 1] = y; out_kxyz[o + 2] = z;
#pragma unroll
        for (int i = 0; i < 3; i++)
            kxyz_t[o + i] = R[i * 3 + 0] * x + R[i * 3 + 1] * y + R[i * 3 + 2] * z;
    }
}

// ---------------- K3: radius grouping + src dfe + maxpool ----------------
__global__ __launch_bounds__(64)
void k_group_emb(const float* __restrict__ kxyz, const int* __restrict__ key_idx,
                 const float* __restrict__ src_feat,
                 const float* __restrict__ Wd1, const float* __restrict__ bd1,
                 const float* __restrict__ Wd2, const float* __restrict__ bd2,
                 float* __restrict__ src_emb)
{
    int b = blockIdx.x / KK, kk = blockIdx.x % KK;
    int t = threadIdx.x;
    __shared__ float kx[KK][3];
    __shared__ float emb[NSZ][FF];
    kx[t][0] = kxyz[(b * KK + t) * 3 + 0];
    kx[t][1] = kxyz[(b * KK + t) * 3 + 1];
    kx[t][2] = kxyz[(b * KK + t) * 3 + 2];
    __syncthreads();
    float cx = kx[kk][0], cy = kx[kk][1], cz = kx[kk][2];
    float dx = kx[t][0] - cx, dy = kx[t][1] - cy, dz = kx[t][2] - cz;
    float sq = dx * dx + dy * dy + dz * dz;
    unsigned long long mask = __ballot(sq <= RAD2);
    if (t < NSZ) {
        int cnt = __popcll(mask);
        int want = (t < cnt) ? t : 0;
        unsigned long long mm = mask;
        for (int q = 0; q < want; q++) mm &= (mm - 1);
        int g = __ffsll(mm) - 1;
        float xr = kx[g][0] - cx, yr = kx[g][1] - cy, zr = kx[g][2] - cz;
        int orig = key_idx[b * KK + g];
        const float* fz = &src_feat[(b * NPTS + orig) * FF];
        float fr[FF];
#pragma unroll
        for (int i = 0; i < FF; i++) fr[i] = fz[i];
        float h[FF];
#pragma unroll
        for (int j = 0; j < FF; j++) {
            float a = bd1[j];
            a = fmaf(xr, Wd1[0 * FF + j], a);
            a = fmaf(yr, Wd1[1 * FF + j], a);
            a = fmaf(zr, Wd1[2 * FF + j], a);
#pragma unroll
            for (int i = 0; i < FF; i++) a = fmaf(fr[i], Wd1[(3 + i) * FF + j], a);
            h[j] = fmaxf(a, 0.0f);
        }
#pragma unroll
        for (int j = 0; j < FF; j++) {
            float a = bd2[j];
#pragma unroll
            for (int i = 0; i < FF; i++) a = fmaf(h[i], Wd2[i * FF + j], a);
            emb[t][j] = fmaxf(a, 0.0f);
        }
    }
    __syncthreads();
    if (t < FF) {
        float m = emb[0][t];
#pragma unroll
        for (int s2 = 1; s2 < NSZ; s2++) m = fmaxf(m, emb[s2][t]);
        src_emb[(b * KK + kk) * FF + t] = m;
    }
}

// ---------------- K4: fused NN argmin + dfe + sim. 8 waves, 8 n-chunks of 128 ------
// Block: 512 threads = 8 ngroups x 64 lanes, covers 256 candidates x all 1024 points.
// Same total VALU/DS work as the 4-wave version but 2x the waves/CU for latency hiding.
__global__ __launch_bounds__(512)
void k_nn_mlp(const float* __restrict__ kxyz_t, const float* __restrict__ tgt_m2,
              const float* __restrict__ tgt_feat, const float* __restrict__ src_emb,
              const float* __restrict__ Wd1, const float* __restrict__ bd1,
              const float* __restrict__ Wd2, const float* __restrict__ bd2,
              float* __restrict__ sim)
{
    const int CHUNKS = 6;                 // ceil(1331/256)
    int bid = blockIdx.x;
    int chunk = bid % CHUNKS;
    int bk = bid / CHUNKS;                // 0..127
    int b = bk >> 6;
    int t = threadIdx.x;
    int lane = t & 63;
    int ng = t >> 6;                      // 0..7, wave-uniform
    __shared__ float4 P[NPTS];            // 16 KB
    __shared__ float2 mb[8][256];         // 16 KB
    const float4* gp = (const float4*)tgt_m2 + (b << 10);
    for (int i = t; i < NPTS; i += 512) P[i] = gp[i];
    float kx = kxyz_t[bk * 3 + 0], ky = kxyz_t[bk * 3 + 1], kz = kxyz_t[bk * 3 + 2];
    float cxq[4], cyq[4], czq[4], best[4];
    int bn[4];
#pragma unroll
    for (int q = 0; q < 4; q++) {
        int c = chunk * 256 + q * 64 + lane;
        int cc = min(c, CC - 1);
        int ixv = cc / 121, rem = cc - ixv * 121, iyv = rem / 11, izv = rem - iyv * 11;
        cxq[q] = kx + (-2.0f + ixv * 0.4f);
        cyq[q] = ky + (-2.0f + iyv * 0.4f);
        czq[q] = kz + (-2.0f + izv * 0.4f);
        best[q] = 3.0e38f; bn[q] = 0;
    }
    __syncthreads();
    const int base = ng << 7;             // 128 points per wave
#pragma unroll 8
    for (int i = 0; i < 128; i++) {
        float4 v = P[base + i];           // wave-uniform addr -> LDS broadcast
#pragma unroll
        for (int q = 0; q < 4; q++) {
            float d = fmaf(cxq[q], v.x, fmaf(cyq[q], v.y, fmaf(czq[q], v.z, v.w)));
            bool lt = d < best[q];        // strict <: first-min within chunk
            best[q] = lt ? d : best[q];
            bn[q] = lt ? (base + i) : bn[q];
        }
    }
#pragma unroll
    for (int q = 0; q < 4; q++)
        mb[ng][q * 64 + lane] = make_float2(best[q], __int_as_float(bn[q]));
    __syncthreads();
    if (t >= 256) return;                 // no barriers after this point
    // merge: thread t owns candidate c = chunk*256 + t; ascending ng, strict <
    float2 r = mb[0][t];
#pragma unroll
    for (int g = 1; g < 8; g++) {
        float2 o = mb[g][t];
        if (o.x < r.x) r = o;             // ties -> lower ng -> lower n: matches argmin
    }
    int nb = __float_as_int(r.y);
    int c = chunk * 256 + t;
    int cc = min(c, CC - 1);
    int ixv = cc / 121, rem = cc - ixv * 121, iyv = rem / 11, izv = rem - iyv * 11;
    float cx = kx + (-2.0f + ixv * 0.4f);
    float cy = ky + (-2.0f + iyv * 0.4f);
    float cz = kz + (-2.0f + izv * 0.4f);
    float4 nv = P[nb];
    // nv = (-2x,-2y,-2z,|t|^2): cand - x == fmaf(0.5, nv.x, cx) exactly
    float x0 = fmaf(0.5f, nv.x, cx);
    float x1 = fmaf(0.5f, nv.y, cy);
    float x2 = fmaf(0.5f, nv.z, cz);
    const float4* fz = (const float4*)&tgt_feat[((b << 10) + nb) * FF];
    float fr[FF];
#pragma unroll
    for (int i = 0; i < FF / 4; i++) {
        float4 v = fz[i];
        fr[i * 4 + 0] = v.x; fr[i * 4 + 1] = v.y; fr[i * 4 + 2] = v.z; fr[i * 4 + 3] = v.w;
    }
    float h[FF];
#pragma unroll
    for (int j = 0; j < FF; j++) {
        float a = bd1[j];                 // uniform -> scalar load
        a = fmaf(x0, Wd1[0 * FF + j], a);
        a = fmaf(x1, Wd1[1 * FF + j], a);
        a = fmaf(x2, Wd1[2 * FF + j], a);
        h[j] = a;
    }
#pragma unroll
    for (int i = 0; i < FF; i++) {
        float fi = fr[i];
#pragma unroll
        for (int j = 0; j < FF; j++)
            h[j] = fmaf(fi, Wd1[(3 + i) * FF + j], h[j]);
    }
#pragma unroll
    for (int j = 0; j < FF; j++) h[j] = fmaxf(h[j], 0.0f);
    float sv = 0.0f;
#pragma unroll
    for (int j = 0; j < FF; j++) {
        float a = bd2[j];
#pragma unroll
        for (int i = 0; i < FF; i++) a = fmaf(h[i], Wd2[i * FF + j], a);
        sv = fmaf(fmaxf(a, 0.0f), src_emb[bk * FF + j], sv);
    }
    if (c < CC) sim[bk * CC + c] = sv;
}

// ---------------- K5: softmax over candidates + weighted sum ----------------
__global__ __launch_bounds__(256)
void k_softmax(const float* __restrict__ sim, const float* __restrict__ kxyz_t,
               float* __restrict__ out_vcp)
{
    int bk = blockIdx.x;
    int t = threadIdx.x;
    __shared__ float red[256];
    __shared__ float4 red4[256];
    float kx = kxyz_t[bk * 3 + 0], ky = kxyz_t[bk * 3 + 1], kz = kxyz_t[bk * 3 + 2];
    float lm = -3.0e38f;
    for (int c = t; c < CC; c += 256) lm = fmaxf(lm, sim[bk * CC + c]);
    red[t] = lm;
    __syncthreads();
    for (int s2 = 128; s2 > 0; s2 >>= 1) {
        if (t < s2) red[t] = fmaxf(red[t], red[t + s2]);
        __syncthreads();
    }
    float m = red[0];
    float se = 0.f, sx = 0.f, sy = 0.f, sz = 0.f;
    for (int c = t; c < CC; c += 256) {
        float e = expf(sim[bk * CC + c] - m);
        int ix = c / 121, rem = c - ix * 121, iy = rem / 11, iz = rem - iy * 11;
        float cxx = kx + (-2.0f + ix * 0.4f);
        float cyy = ky + (-2.0f + iy * 0.4f);
        float czz = kz + (-2.0f + iz * 0.4f);
        se += e;
        sx = fmaf(e, cxx, sx);
        sy = fmaf(e, cyy, sy);
        sz = fmaf(e, czz, sz);
    }
    red4[t] = make_float4(se, sx, sy, sz);
    __syncthreads();
    for (int s2 = 128; s2 > 0; s2 >>= 1) {
        if (t < s2) {
            float4 a = red4[t], bq = red4[t + s2];
            red4[t] = make_float4(a.x + bq.x, a.y + bq.y, a.z + bq.z, a.w + bq.w);
        }
        __syncthreads();
    }
    if (t == 0) {
        float4 r = red4[0];
        out_vcp[bk * 3 + 0] = r.y / r.x;
        out_vcp[bk * 3 + 1] = r.z / r.x;
        out_vcp[bk * 3 + 2] = r.w / r.x;
    }
}

extern "C" void kernel_launch(void* const* d_in, const int* in_sizes, int n_in,
                              void* d_out, int out_size, void* d_ws, size_t ws_size,
                              hipStream_t stream)
{
    (void)in_sizes; (void)n_in; (void)out_size; (void)ws_size;
    const float* src_pts = (const float*)d_in[0];
    const float* tgt_pts = (const float*)d_in[1];
    const float* R_init  = (const float*)d_in[2];
    const float* W1  = (const float*)d_in[4];
    const float* b1  = (const float*)d_in[5];
    const float* W2  = (const float*)d_in[6];
    const float* b2  = (const float*)d_in[7];
    const float* Ww1 = (const float*)d_in[8];
    const float* bw1 = (const float*)d_in[9];
    const float* Ww2 = (const float*)d_in[10];
    const float* bw2 = (const float*)d_in[11];
    const float* Wd1 = (const float*)d_in[12];
    const float* bd1 = (const float*)d_in[13];
    const float* Wd2 = (const float*)d_in[14];
    const float* bd2 = (const float*)d_in[15];

    float* ws = (float*)d_ws;
    float* src_feat = ws;                              // B*N*F   = 65536
    float* tgt_feat = src_feat + BB * NPTS * FF;       // 65536
    float* tgt_m2   = tgt_feat + BB * NPTS * FF;       // B*N*4   = 8192
    float* score    = tgt_m2 + BB * NPTS * 4;          // 2048
    int*   key_idx  = (int*)(score + BB * NPTS);       // 128
    float* kxyz     = (float*)(key_idx + BB * KK);     // 384
    float* kxyz_t   = kxyz + BB * KK * 3;              // 384
    float* src_emb  = kxyz_t + BB * KK * 3;            // 4096
    float* sim      = src_emb + BB * KK * FF;          // B*K*C = 170368

    float* out_kxyz = (float*)d_out;
    float* out_vcp  = out_kxyz + BB * KK * 3;

    k_features<<<64, 64, 0, stream>>>(
        src_pts, tgt_pts, W1, b1, W2, b2, Ww1, bw1, Ww2, bw2,
        src_feat, tgt_feat, tgt_m2, score);
    k_topk<<<BB, 1024, 0, stream>>>(score, src_pts, R_init,
                                    key_idx, kxyz, kxyz_t, out_kxyz);
    k_group_emb<<<BB * KK, 64, 0, stream>>>(kxyz, key_idx, src_feat,
                                            Wd1, bd1, Wd2, bd2, src_emb);
    k_nn_mlp<<<BB * KK * 6, 512, 0, stream>>>(kxyz_t, tgt_m2, tgt_feat, src_emb,
                                              Wd1, bd1, Wd2, bd2, sim);
    k_softmax<<<BB * KK, 256, 0, stream>>>(sim, kxyz_t, out_vcp);
}